// Round 10
// baseline (3913.760 us; speedup 1.0000x reference)
//
#include <hip/hip_runtime.h>
#include <hip/hip_bf16.h>
#include <stdint.h>

#define Tn 512
#define Bn 64
#define Hn 512
#define LDP 520           // LDS row pitch (u16)
#define NWG 128
#define NTHR 512

typedef unsigned short u16;
typedef unsigned int u32;
typedef unsigned long long u64;
typedef __attribute__((ext_vector_type(8))) short bf16x8;
typedef __attribute__((ext_vector_type(4))) float f32x4;

// ws layout:
//   u32 idx 0    : arrive[128] lines (64B apart)              8KB
//   u32 idx 2048 : cross_arrive[64] lines ((sg*16+cc)*16)     4KB
//   u32 idx 3072 : cross_staged[64] lines                     4KB
//   byte 16384   : h_ring [2][4 sg][4 slot][16 samp][512] bf16  512KB
//   byte 540672  : xbf [Tn][Bn][Hn] bf16 (32MB), if xok
#define CARR_OFF 2048
#define CSTG_OFF 3072
#define RING_OFF 16384
#define XBF_OFF  540672

__device__ __forceinline__ u16 f2bf(float f) {
  u32 u = __float_as_uint(f);
  u = (u + 0x7FFFu + ((u >> 16) & 1u)) >> 16;   // RNE
  return (u16)u;
}
__device__ __forceinline__ float sigf(float x) { return 1.f / (1.f + __expf(-x)); }
__device__ __forceinline__ float mytanh(float x) {
  float e = __expf(2.f * x);
  return 1.f - 2.f / (e + 1.f);
}

// ---------- pre-kernel: x -> bf16, hx -> ring slot 3 (t = -1) ----------
extern "C" __global__ void __launch_bounds__(256)
lstm_prep(const float* __restrict__ x, const float* __restrict__ hx,
          u32* __restrict__ ws, int xok) {
  u16* ring = (u16*)((char*)ws + RING_OFF);
  u16* xbf  = (u16*)((char*)ws + XBF_OFF);
  const int gt = blockIdx.x * 256 + threadIdx.x;   // 0..524287
  if (xok) {
#pragma unroll
    for (int i = 0; i < 8; ++i) {
      const int c = gt + (i << 19);                // float4 chunk id
      const float4 v = *(const float4*)(x + (size_t)c * 4);
      const u64 pk = (u64)((u32)f2bf(v.x) | ((u32)f2bf(v.y) << 16)) |
                     ((u64)((u32)f2bf(v.z) | ((u32)f2bf(v.w) << 16)) << 32);
      *(u64*)(xbf + (size_t)c * 4) = pk;
    }
  }
  if (gt < 32768) {
    const int e0 = 2 * gt;
    const int l = e0 >> 15;
    const int rem = e0 & 32767;
    const int b = rem >> 9, c = rem & 511;
    const int sg = b >> 4, samp = b & 15;
    const u32 pk = (u32)f2bf(hx[e0]) | ((u32)f2bf(hx[e0 + 1]) << 16);
    *(u32*)(ring + (size_t)(l * 4 + sg) * 32768 + 3 * 8192 + samp * 512 + c) = pk;
  }
}

// ---------- main persistent cooperative kernel ----------
extern "C" __global__ void __launch_bounds__(NTHR, 1)
lstm_fused(const float* __restrict__ x, const float* __restrict__ hx,
           const float* __restrict__ cx, const float* __restrict__ Wih,
           const float* __restrict__ Whh, const float* __restrict__ bih,
           const float* __restrict__ bhh, float* __restrict__ out,
           u32* __restrict__ ws, int xok) {
  __shared__ u16 sh_inp[16 * LDP];
  __shared__ u16 sh_h[16 * LDP];
  __shared__ u32 sh_flag;

  const int wg = blockIdx.x;
  const int tid = threadIdx.x;
  const int gid = wg >> 4;          // group 0..7
  const int layer = gid >> 2;       // 0..1
  const int sg = gid & 3;           // sample group (16 samples)
  const int cc = wg & 15;           // column chunk (32 cols)
  const int wave = tid >> 6;        // 0..7  (= row-tile mt)
  const int lane = tid & 63;
  const int l15 = lane & 15;
  const int lhi = lane >> 4;
  const int mt = wave;

  u32* arrive = ws;                                  // arrive[w] = ws[w*16]
  u32* carr = ws + CARR_OFF;                         // cross_arrive lines
  u32* cstg = ws + CSTG_OFF;                         // cross_staged lines
  u16* ring = (u16*)((char*)ws + RING_OFF);
  u16* xbf  = (u16*)((char*)ws + XBF_OFF);
  u16* ring_my = ring + (size_t)(layer * 4 + sg) * 32768;
  u16* ring_l0 = ring + (size_t)sg * 32768;

  if (tid == 0) sh_flag = 0;

  // ---- weights -> registers. WG rows (128): j = colLocal*4 + gate ----
  const int jrow = mt * 16 + l15;
  const int gateA = jrow & 3, colA = jrow >> 2;      // colA in [mt*4, mt*4+3]
  const int growA = gateA * Hn + cc * 32 + colA;
  const float* wihp = Wih + ((size_t)layer * 4 * Hn + growA) * Hn;
  const float* whhp = Whh + ((size_t)layer * 4 * Hn + growA) * Hn;
  bf16x8 wih_f[16], whh_f[16];
#pragma unroll
  for (int kt = 0; kt < 16; ++kt) {
    const int k0 = kt * 32 + lhi * 8;
    const float4 va0 = *(const float4*)(wihp + k0);
    const float4 va1 = *(const float4*)(wihp + k0 + 4);
    const float4 vb0 = *(const float4*)(whhp + k0);
    const float4 vb1 = *(const float4*)(whhp + k0 + 4);
    bf16x8 a, b;
    a[0]=(short)f2bf(va0.x); a[1]=(short)f2bf(va0.y); a[2]=(short)f2bf(va0.z); a[3]=(short)f2bf(va0.w);
    a[4]=(short)f2bf(va1.x); a[5]=(short)f2bf(va1.y); a[6]=(short)f2bf(va1.z); a[7]=(short)f2bf(va1.w);
    b[0]=(short)f2bf(vb0.x); b[1]=(short)f2bf(vb0.y); b[2]=(short)f2bf(vb0.z); b[3]=(short)f2bf(vb0.w);
    b[4]=(short)f2bf(vb1.x); b[5]=(short)f2bf(vb1.y); b[6]=(short)f2bf(vb1.z); b[7]=(short)f2bf(vb1.w);
    wih_f[kt] = a; whh_f[kt] = b;
  }

  // ---- elementwise mapping: acc reg r == gate r for (sampE, colE) ----
  const int colE = cc * 32 + mt * 4 + lhi;
  const int sampE = sg * 16 + l15;
  float bias[4];
#pragma unroll
  for (int r = 0; r < 4; ++r) {
    const int grow = r * Hn + cc * 32 + mt * 4 + lhi;
    bias[r] = bih[layer * 4 * Hn + grow] + bhh[layer * 4 * Hn + grow];
  }
  float c_cur = cx[((size_t)layer * Bn + sampE) * Hn + colE];

  // stage x(t) -> sh_inp (layer 0 shadow)
  auto stage_x = [&](int t) {
    if (xok) {
      const u16* ip = xbf + ((size_t)t * Bn + sg * 16) * Hn;
#pragma unroll
      for (int i = 0; i < 2; ++i) {
        const int chunk = tid + i * 512;             // 1024 chunks of 8 bf16
        const int row = chunk >> 6, c0 = (chunk & 63) * 8;
        const uint4 v = *(const uint4*)(ip + (size_t)row * Hn + c0);
        *(uint4*)(&sh_inp[row * LDP + c0]) = v;
      }
    } else {
      const float* xp = x + ((size_t)t * Bn + sg * 16) * Hn;
#pragma unroll
      for (int i = 0; i < 4; ++i) {
        const int chunk = tid + i * 512;             // 2048 chunks of 4 floats
        const int row = chunk >> 7, c0 = (chunk & 127) * 4;
        const float4 v = *(const float4*)(xp + (size_t)row * Hn + c0);
        const u32 p0 = (u32)f2bf(v.x) | ((u32)f2bf(v.y) << 16);
        const u32 p1 = (u32)f2bf(v.z) | ((u32)f2bf(v.w) << 16);
        *(uint2*)(&sh_inp[row * LDP + c0]) = make_uint2(p0, p1);
      }
    }
  };
  // stage h0(u) -> sh_inp (layer 1 shadow), agent loads from L0's ring
  auto stage_h0 = [&](int u) {
    const u16* ip = ring_l0 + (size_t)(u & 3) * 8192;
#pragma unroll
    for (int i = 0; i < 4; ++i) {
      const int chunk = tid + i * 512;               // 2048 chunks of 8B
      const int row = chunk >> 7, c0 = (chunk & 127) * 4;
      const u64 v = __hip_atomic_load((const u64*)(ip + row * 512 + c0),
                                      __ATOMIC_RELAXED, __HIP_MEMORY_SCOPE_AGENT);
      *(u64*)(&sh_inp[row * LDP + c0]) = v;
    }
  };

  // ---- pre-loop shadow: input(0) + ih-GEMM for layer 0 ----
  if (layer == 0) stage_x(0);
  __syncthreads();
  f32x4 aI0 = {0.f,0.f,0.f,0.f}, aI1 = {0.f,0.f,0.f,0.f};
  if (layer == 0) {
#pragma unroll
    for (int kt = 0; kt < 16; kt += 2) {
      const bf16x8 bi0 = *(const bf16x8*)(&sh_inp[l15 * LDP + kt * 32 + lhi * 8]);
      const bf16x8 bi1 = *(const bf16x8*)(&sh_inp[l15 * LDP + (kt + 1) * 32 + lhi * 8]);
      aI0 = __builtin_amdgcn_mfma_f32_16x16x32_bf16(wih_f[kt], bi0, aI0, 0, 0, 0);
      aI1 = __builtin_amdgcn_mfma_f32_16x16x32_bf16(wih_f[kt + 1], bi1, aI1, 0, 0, 0);
    }
  }

  const int smax = layer ? (Tn + 2) : (Tn - 1);      // 514 : 511
  for (int s = 0; s <= smax; ++s) {
    const int t = layer ? s - 3 : s;
    const bool act = (t >= 0) && (t < Tn);

    // ---------- critical phase ----------
    if (act) {
      // restage own h(t-1), slot (t-1)&3 (t=0 -> slot 3 = init)
      const u16* hp = ring_my + (size_t)((t - 1) & 3) * 8192;
#pragma unroll
      for (int i = 0; i < 4; ++i) {
        const int chunk = tid + i * 512;
        const int row = chunk >> 7, c0 = (chunk & 127) * 4;
        const u64 v = __hip_atomic_load((const u64*)(hp + row * 512 + c0),
                                        __ATOMIC_RELAXED, __HIP_MEMORY_SCOPE_AGENT);
        *(u64*)(&sh_h[row * LDP + c0]) = v;
      }
    }
    __syncthreads();

    float hn = 0.f, cn = 0.f;
    if (act) {
      f32x4 b0 = {0.f,0.f,0.f,0.f}, b1 = {0.f,0.f,0.f,0.f};
#pragma unroll
      for (int kt = 0; kt < 16; kt += 2) {
        const bf16x8 bh0 = *(const bf16x8*)(&sh_h[l15 * LDP + kt * 32 + lhi * 8]);
        const bf16x8 bh1 = *(const bf16x8*)(&sh_h[l15 * LDP + (kt + 1) * 32 + lhi * 8]);
        b0 = __builtin_amdgcn_mfma_f32_16x16x32_bf16(whh_f[kt], bh0, b0, 0, 0, 0);
        b1 = __builtin_amdgcn_mfma_f32_16x16x32_bf16(whh_f[kt + 1], bh1, b1, 0, 0, 0);
      }
      const float gi = aI0[0] + aI1[0] + b0[0] + b1[0] + bias[0];
      const float gf = aI0[1] + aI1[1] + b0[1] + b1[1] + bias[1];
      const float gg = aI0[2] + aI1[2] + b0[2] + b1[2] + bias[2];
      const float go_ = aI0[3] + aI1[3] + b0[3] + b1[3] + bias[3];
      cn = sigf(gf) * c_cur + sigf(gi) * mytanh(gg);
      hn = sigf(go_) * mytanh(cn);
      c_cur = cn;

      // pack 4 cols -> 8B agent store into own ring slot t&3
      const u32 hu = (u32)f2bf(hn);
      const u32 pair = hu | (__shfl_xor(hu, 16) << 16);
      const u32 hi2 = __shfl_xor(pair, 32);
      if (lhi == 0) {
        const u64 v8 = (u64)pair | ((u64)hi2 << 32);
        u16* wp = ring_my + (size_t)(t & 3) * 8192 + l15 * 512 + cc * 32 + mt * 4;
        __hip_atomic_store((u64*)wp, v8, __ATOMIC_RELAXED, __HIP_MEMORY_SCOPE_AGENT);
      }
    }
    // drain all waves' stores, then RELEASE-publish arrival (+cross for L0)
    asm volatile("s_waitcnt vmcnt(0)" ::: "memory");
    __syncthreads();
    if (tid == 0) {
      __hip_atomic_store(&arrive[wg * 16], (u32)(s + 1),
                         __ATOMIC_RELEASE, __HIP_MEMORY_SCOPE_AGENT);
      if (layer == 0)
        __hip_atomic_store(&carr[(sg * 16 + cc) * 16], (u32)(s + 1),
                           __ATOMIC_RELEASE, __HIP_MEMORY_SCOPE_AGENT);
    }

    // ---------- shadow phase (off the group critical path) ----------
    if (act) {
      if (layer == 1)
        out[((size_t)t * Bn + sampE) * Hn + colE] = hn;
      if (t == Tn - 1) {
        out[(size_t)Tn * Bn * Hn + ((size_t)layer * Bn + sampE) * Hn + colE] = hn;
        out[(size_t)Tn * Bn * Hn + (size_t)2 * Bn * Hn + ((size_t)layer * Bn + sampE) * Hn + colE] = cn;
      }
    }
    bool ihnext = false;
    if (layer == 0) {
      if (s + 1 <= Tn - 1) { stage_x(s + 1); ihnext = true; }
    } else if (s >= 2 && s - 2 <= Tn - 1) {
      // cross RAW: need L0 group done with step s-2 (flag ~2 periods old)
      const u32* pl = &carr[(sg * 16 + (lane & 15)) * 16];
      while (true) {
        const u32 v = __hip_atomic_load(pl, __ATOMIC_RELAXED, __HIP_MEMORY_SCOPE_AGENT);
        if (__all((int)(v >= (u32)(s - 1)))) break;
        __builtin_amdgcn_s_sleep(1);
      }
      stage_h0(s - 2);
      ihnext = true;
    }
    __syncthreads();   // sh_inp staged for step s+1
    if (ihnext) {
      aI0 = (f32x4){0.f,0.f,0.f,0.f}; aI1 = (f32x4){0.f,0.f,0.f,0.f};
#pragma unroll
      for (int kt = 0; kt < 16; kt += 2) {
        const bf16x8 bi0 = *(const bf16x8*)(&sh_inp[l15 * LDP + kt * 32 + lhi * 8]);
        const bf16x8 bi1 = *(const bf16x8*)(&sh_inp[l15 * LDP + (kt + 1) * 32 + lhi * 8]);
        aI0 = __builtin_amdgcn_mfma_f32_16x16x32_bf16(wih_f[kt], bi0, aI0, 0, 0, 0);
        aI1 = __builtin_amdgcn_mfma_f32_16x16x32_bf16(wih_f[kt + 1], bi1, aI1, 0, 0, 0);
      }
    }
    if (layer == 1 && s >= 2 && s - 2 <= Tn - 1 && tid == 0)
      __hip_atomic_store(&cstg[(sg * 16 + cc) * 16], (u32)(s + 1),
                         __ATOMIC_RELAXED, __HIP_MEMORY_SCOPE_AGENT);
    if (layer == 0 && s >= 3 && s <= Tn - 2) {
      // cross WAR: ring slot (s+1)&3 free once L1 staged h0[s-3] (flag ~2 periods old)
      const u32* pl = &cstg[(sg * 16 + (lane & 15)) * 16];
      while (true) {
        const u32 v = __hip_atomic_load(pl, __ATOMIC_RELAXED, __HIP_MEMORY_SCOPE_AGENT);
        if (__all((int)(v >= (u32)s))) break;
        __builtin_amdgcn_s_sleep(1);
      }
    }

    if (s == smax) break;

    // ---------- flat 16-line group barrier ----------
    const u32 target = (u32)(s + 1);
    if (wave == 0) {
      const u32* pl = &arrive[(gid * 16 + (lane & 15)) * 16];
      while (true) {
        const u32 v = __hip_atomic_load(pl, __ATOMIC_RELAXED, __HIP_MEMORY_SCOPE_AGENT);
        if (__all((int)(v >= target))) break;
        __builtin_amdgcn_s_sleep(1);
      }
      __hip_atomic_store(&sh_flag, target, __ATOMIC_RELAXED, __HIP_MEMORY_SCOPE_WORKGROUP);
    } else {
      while (__hip_atomic_load(&sh_flag, __ATOMIC_RELAXED, __HIP_MEMORY_SCOPE_WORKGROUP) < target)
        __builtin_amdgcn_s_sleep(1);
    }
    asm volatile("" ::: "memory");
  }
}

extern "C" void kernel_launch(void* const* d_in, const int* in_sizes, int n_in,
                              void* d_out, int out_size, void* d_ws, size_t ws_size,
                              hipStream_t stream) {
  const float* x   = (const float*)d_in[0];
  const float* hx  = (const float*)d_in[1];
  const float* cx  = (const float*)d_in[2];
  const float* Wih = (const float*)d_in[3];
  const float* Whh = (const float*)d_in[4];
  const float* bih = (const float*)d_in[5];
  const float* bhh = (const float*)d_in[6];
  float* outp = (float*)d_out;
  u32* wsp = (u32*)d_ws;

  const size_t need = (size_t)XBF_OFF + (size_t)Tn * Bn * Hn * 2;
  int xok = (ws_size >= need) ? 1 : 0;

  hipMemsetAsync(d_ws, 0, RING_OFF, stream);   // zero all flag lines every call

  lstm_prep<<<dim3(2048), dim3(256), 0, stream>>>(x, hx, wsp, xok);

  void* args[] = {(void*)&x, (void*)&hx, (void*)&cx, (void*)&Wih, (void*)&Whh,
                  (void*)&bih, (void*)&bhh, (void*)&outp, (void*)&wsp, (void*)&xok};
  hipError_t e = hipLaunchCooperativeKernel((const void*)lstm_fused, dim3(NWG),
                                            dim3(NTHR), args, 0, stream);
  if (e != hipSuccess) {
    lstm_fused<<<dim3(NWG), dim3(NTHR), 0, stream>>>(x, hx, cx, Wih, Whh, bih, bhh, outp, wsp, xok);
  }
}